// Round 6
// baseline (291.425 us; speedup 1.0000x reference)
//
#include <hip/hip_runtime.h>

// OSNAP sketch: out[n,f] = sum_d x[n,d] * P[f,d]
// x: [16384,4096] f32. P: [8192,4096] f32, exactly 4 nonzeros (+-0.5) per COLUMN.
// v6: persistent double-buffered gather. Each block owns 8 groups of 4 x-rows;
// next group's rows stream into the other LDS buffer via global_load_lds(16B)
// while the current group computes. ent4 structure is hoisted into registers
// once per block. Extraction fused to 3 kernels.

#define D_IN    4096
#define D_FEAT  8192
#define N_TOT   16384
#define CAP     16        // per-row clamp (P(Poisson(2) >= 16) ~ 4e-10 per row)
#define NR      4         // x-rows per group
#define FPT     4         // features per thread per half
#define PADW    8         // pad words per LDS row (zero slot for dummy entries)
#define ROWW    (D_IN + PADW)       // 4104 words
#define BUFW    (NR * ROWW)         // 16416 words = 65664 B per buffer
#define GPB     8                   // groups per block
#define OVF_CAP 16384

typedef float f32x4 __attribute__((ext_vector_type(4)));

// ---------------- ws layout (bytes, NO overlaps) ----------------
// 0        row_cnt  int  [D_FEAT]      32768
// 32768    row_ent  int2 [D_FEAT*CAP]  1048576 -> 1081344  (.x=d, .y=bits(val))
// 1081344  ent4     int4 [D_FEAT]      131072  -> 1212416  (4 packed entries/row)
// 1212416  ovf_desc int  [D_FEAT]      32768   -> 1245184  ((start<<5)|extra)
// 1245184  ovf_ents int  [OVF_CAP]     65536   -> 1310720
// 1310720  ovf_base int  [1]           4

__global__ void k_zero(int* __restrict__ row_cnt, int* __restrict__ ovf_base) {
    int t = blockIdx.x * blockDim.x + threadIdx.x;
    if (t < D_FEAT) row_cnt[t] = 0;
    if (t == 0)     ovf_base[0] = 0;
}

// Full-BW streaming scan of P (128MB), binning nonzeros directly into row lists.
__global__ void k_scan(const f32x4* __restrict__ p4,
                       int* __restrict__ row_cnt, int2* __restrict__ row_ent) {
    const long total = (long)D_FEAT * D_IN / 4;
    for (long q = (long)blockIdx.x * blockDim.x + threadIdx.x; q < total;
         q += (long)gridDim.x * blockDim.x) {
        f32x4 v = __builtin_nontemporal_load(&p4[q]);
        long base = q * 4;
        float vals[4] = {v.x, v.y, v.z, v.w};
        #pragma unroll
        for (int c = 0; c < 4; ++c) {
            if (vals[c] != 0.0f) {
                long i = base + c;
                int f = (int)(i >> 12);          // / D_IN
                int d = (int)(i & (D_IN - 1));   // % D_IN
                int slot = atomicAdd(&row_cnt[f], 1);
                if (slot < CAP) row_ent[f * CAP + slot] = make_int2(d, __float_as_int(vals[c]));
            }
        }
    }
}

// Per row f: sort entries by d (distinct -> deterministic), pack first 4 into
// int4 (entry = d*4 | sign<<31; dummy = D_IN*4 -> zeroed pad word; bit30 of .w =
// overflow flag), extras -> atomically-allocated compact slab. Slab offsets vary
// run-to-run but per-row entry ORDER doesn't -> bitwise-deterministic output.
__global__ void k_sortpack(const int* __restrict__ row_cnt, int2* __restrict__ row_ent,
                           int4* __restrict__ ent4, int* __restrict__ ovf_desc,
                           int* __restrict__ ovf_ents, int* __restrict__ ovf_base) {
    int f = blockIdx.x * blockDim.x + threadIdx.x;
    if (f >= D_FEAT) return;
    int cnt = row_cnt[f];
    if (cnt > CAP) cnt = CAP;
    for (int a = 1; a < cnt; ++a) {
        int2 key = row_ent[f * CAP + a];
        int b = a - 1;
        while (b >= 0) {
            int2 cur = row_ent[f * CAP + b];
            if (cur.x <= key.x) break;
            row_ent[f * CAP + b + 1] = cur;
            --b;
        }
        row_ent[f * CAP + b + 1] = key;
    }
    int e[4];
    #pragma unroll
    for (int j = 0; j < 4; ++j) {
        if (j < cnt) {
            int2 ev = row_ent[f * CAP + j];
            e[j] = (ev.x * 4) | (int)((unsigned)ev.y & 0x80000000u);
        } else {
            e[j] = D_IN * 4;   // dummy -> zeroed pad word
        }
    }
    int extra = (cnt > 4) ? (cnt - 4) : 0;
    int start = 0;
    if (extra) {
        start = atomicAdd(ovf_base, extra);
        if (start < 0) start = 0;
        if (start > OVF_CAP - CAP) start = OVF_CAP - CAP;   // capacity guard
        for (int j = 0; j < extra; ++j) {
            int2 ev = row_ent[f * CAP + 4 + j];
            ovf_ents[start + j] = (ev.x * 4) | (int)((unsigned)ev.y & 0x80000000u);
        }
        e[3] |= 0x40000000;
    }
    ovf_desc[f] = (start << 5) | extra;
    ent4[f] = make_int4(e[0], e[1], e[2], e[3]);
}

// Direct global->LDS 16B async copy (no VGPR round-trip). LDS dest is
// wave-uniform base + lane*16; global src is per-lane.
__device__ __forceinline__ void load_lds16(const float* g, float* l) {
    __builtin_amdgcn_global_load_lds(
        (const __attribute__((address_space(1))) void*)g,
        (__attribute__((address_space(3))) void*)l, 16, 0, 0);
}

// Persistent double-buffered gather.
__global__ __launch_bounds__(1024, 4) void k_gather(const float* __restrict__ x,
                                                    const int4* __restrict__ ent4,
                                                    const int* __restrict__ ovf_desc,
                                                    const int* __restrict__ ovf_ents,
                                                    float* __restrict__ out) {
    __shared__ float xs[2 * BUFW];        // 131,328 B -> 1 block/CU
    const int tid = threadIdx.x;
    const int wav = tid >> 6;
    const int nb0 = blockIdx.x * (NR * GPB);

    // Hoist the (group-invariant) structure into registers: 8 int4 per thread.
    const int fb0 = tid * FPT;
    const int fb1 = fb0 + D_FEAT / 2;
    const int4 ea0 = ent4[fb0 + 0], ea1 = ent4[fb0 + 1];
    const int4 ea2 = ent4[fb0 + 2], ea3 = ent4[fb0 + 3];
    const int4 eb0 = ent4[fb1 + 0], eb1 = ent4[fb1 + 1];
    const int4 eb2 = ent4[fb1 + 2], eb3 = ent4[fb1 + 3];
    const int ovfA = (ea0.w | ea1.w | ea2.w | ea3.w) & 0x40000000;
    const int ovfB = (eb0.w | eb1.w | eb2.w | eb3.w) & 0x40000000;

    // Zero the pad words of both buffers (dummy entries read word D_IN of row 0).
    if (tid < 2 * NR * PADW) {
        int b = tid >> 5, r = (tid >> 3) & 3, w = tid & 7;
        xs[b * BUFW + r * ROWW + D_IN + w] = 0.f;
    }

    // Stage group G's 4 rows into buffer B: per thread 4x global_load_lds(16B).
    #define STAGE(B, G) { \
        float* lb = xs + (B) * BUFW + wav * 256; \
        const float* gb = x + (size_t)(nb0 + (G) * NR) * D_IN + tid * 4; \
        load_lds16(gb,            lb); \
        load_lds16(gb + D_IN,     lb + ROWW); \
        load_lds16(gb + 2 * D_IN, lb + 2 * ROWW); \
        load_lds16(gb + 3 * D_IN, lb + 3 * ROWW); }

    // ENT adds one packed entry (byte-off | sign<<31) to the 4 row-accumulators.
    #define ENT(EE, A0, A1, A2, A3) { \
        int off_ = (EE) & 0x7FFC; \
        float v0_ = *(const float*)(xb + off_); \
        float v1_ = *(const float*)(xb + off_ + 4 * ROWW); \
        float v2_ = *(const float*)(xb + off_ + 8 * ROWW); \
        float v3_ = *(const float*)(xb + off_ + 12 * ROWW); \
        unsigned sg_ = (unsigned)(EE) & 0x80000000u; \
        A0 += __uint_as_float(__float_as_uint(v0_) ^ sg_); \
        A1 += __uint_as_float(__float_as_uint(v1_) ^ sg_); \
        A2 += __uint_as_float(__float_as_uint(v2_) ^ sg_); \
        A3 += __uint_as_float(__float_as_uint(v3_) ^ sg_); }

    #define HALF(E0, E1, E2, E3, OVF, FB, O0, O1, O2, O3) { \
        float a00=0,a01=0,a02=0,a03=0, a10=0,a11=0,a12=0,a13=0; \
        float a20=0,a21=0,a22=0,a23=0, a30=0,a31=0,a32=0,a33=0; \
        ENT(E0.x,a00,a01,a02,a03) ENT(E0.y,a00,a01,a02,a03) \
        ENT(E0.z,a00,a01,a02,a03) ENT(E0.w,a00,a01,a02,a03) \
        ENT(E1.x,a10,a11,a12,a13) ENT(E1.y,a10,a11,a12,a13) \
        ENT(E1.z,a10,a11,a12,a13) ENT(E1.w,a10,a11,a12,a13) \
        ENT(E2.x,a20,a21,a22,a23) ENT(E2.y,a20,a21,a22,a23) \
        ENT(E2.z,a20,a21,a22,a23) ENT(E2.w,a20,a21,a22,a23) \
        ENT(E3.x,a30,a31,a32,a33) ENT(E3.y,a30,a31,a32,a33) \
        ENT(E3.z,a30,a31,a32,a33) ENT(E3.w,a30,a31,a32,a33) \
        if (OVF) {                                   /* rare overflow tails */ \
            if (E0.w & 0x40000000) { int od = ovf_desc[(FB)+0]; int ex = od & 31; \
                const int* oe = ovf_ents + (od >> 5); \
                for (int j = 0; j < ex; ++j) { int ee = oe[j]; ENT(ee,a00,a01,a02,a03) } } \
            if (E1.w & 0x40000000) { int od = ovf_desc[(FB)+1]; int ex = od & 31; \
                const int* oe = ovf_ents + (od >> 5); \
                for (int j = 0; j < ex; ++j) { int ee = oe[j]; ENT(ee,a10,a11,a12,a13) } } \
            if (E2.w & 0x40000000) { int od = ovf_desc[(FB)+2]; int ex = od & 31; \
                const int* oe = ovf_ents + (od >> 5); \
                for (int j = 0; j < ex; ++j) { int ee = oe[j]; ENT(ee,a20,a21,a22,a23) } } \
            if (E3.w & 0x40000000) { int od = ovf_desc[(FB)+3]; int ex = od & 31; \
                const int* oe = ovf_ents + (od >> 5); \
                for (int j = 0; j < ex; ++j) { int ee = oe[j]; ENT(ee,a30,a31,a32,a33) } } \
        } \
        f32x4 r0 = {a00*0.5f, a10*0.5f, a20*0.5f, a30*0.5f}; \
        f32x4 r1 = {a01*0.5f, a11*0.5f, a21*0.5f, a31*0.5f}; \
        f32x4 r2 = {a02*0.5f, a12*0.5f, a22*0.5f, a32*0.5f}; \
        f32x4 r3 = {a03*0.5f, a13*0.5f, a23*0.5f, a33*0.5f}; \
        __builtin_nontemporal_store(r0, (f32x4*)((O0) + (FB))); \
        __builtin_nontemporal_store(r1, (f32x4*)((O1) + (FB))); \
        __builtin_nontemporal_store(r2, (f32x4*)((O2) + (FB))); \
        __builtin_nontemporal_store(r3, (f32x4*)((O3) + (FB))); }

    STAGE(0, 0);                               // prologue prefetch

    for (int g = 0; g < GPB; ++g) {
        const int cur = g & 1;
        // Barrier's implicit vmcnt(0): buf[cur]'s loads have landed, and every
        // wave is done reading buf[cur^1] -> safe to overwrite it.
        __syncthreads();
        if (g + 1 < GPB) STAGE(cur ^ 1, g + 1);   // in flight during compute
        const char* xb = (const char*)(xs + cur * BUFW);
        const int n0 = nb0 + g * NR;
        float* o0 = out + (size_t)n0 * D_FEAT;
        float* o1 = o0 + D_FEAT;
        float* o2 = o1 + D_FEAT;
        float* o3 = o2 + D_FEAT;
        HALF(ea0, ea1, ea2, ea3, ovfA, fb0, o0, o1, o2, o3)
        HALF(eb0, eb1, eb2, eb3, ovfB, fb1, o0, o1, o2, o3)
    }
    #undef HALF
    #undef ENT
    #undef STAGE
}

extern "C" void kernel_launch(void* const* d_in, const int* in_sizes, int n_in,
                              void* d_out, int out_size, void* d_ws, size_t ws_size,
                              hipStream_t stream) {
    const float* x = (const float*)d_in[0];
    const float* P = (const float*)d_in[1];
    float* out = (float*)d_out;

    char* ws = (char*)d_ws;
    int*   row_cnt  = (int*)  (ws + 0);
    int2*  row_ent  = (int2*) (ws + 32768);
    int4*  ent4     = (int4*) (ws + 1081344);
    int*   ovf_desc = (int*)  (ws + 1212416);
    int*   ovf_ents = (int*)  (ws + 1245184);
    int*   ovf_base = (int*)  (ws + 1310720);

    k_zero    <<<(D_FEAT + 255) / 256, 256, 0, stream>>>(row_cnt, ovf_base);
    k_scan    <<<2048, 256, 0, stream>>>((const f32x4*)P, row_cnt, row_ent);
    k_sortpack<<<(D_FEAT + 255) / 256, 256, 0, stream>>>(row_cnt, row_ent, ent4,
                                                         ovf_desc, ovf_ents, ovf_base);
    k_gather  <<<N_TOT / (NR * GPB), 1024, 0, stream>>>(x, ent4, ovf_desc, ovf_ents, out);
}

// Round 7
// 191.773 us; speedup vs baseline: 1.5196x; 1.5196x over previous
//
#include <hip/hip_runtime.h>

// OSNAP sketch: out[n,f] = sum_d x[n,d] * P[f,d]
// x: [16384,4096] f32. P: [8192,4096] f32, exactly 4 nonzeros (+-0.5) per COLUMN.
// v7 = round-5 gather structure (4096 blocks, 2/CU, one barrier) with
// global_load_lds staging, ent4 prefetch before staging, fused extraction.

#define D_IN    4096
#define D_FEAT  8192
#define N_TOT   16384
#define CAP     16        // per-row clamp (P(Poisson(2) >= 16) ~ 4e-10 per row)
#define NR      4         // x-rows per gather block
#define FPT     4         // features per thread per half
#define PADW    8         // pad words per LDS row (zero slot for dummy entries)
#define ROWW    (D_IN + PADW)       // 4104 words
#define OVF_CAP 16384

typedef float f32x4 __attribute__((ext_vector_type(4)));

// ---------------- ws layout (bytes, NO overlaps) ----------------
// 0        row_cnt  int  [D_FEAT]      32768
// 32768    row_ent  int2 [D_FEAT*CAP]  1048576 -> 1081344  (.x=d, .y=bits(val))
// 1081344  ent4     int4 [D_FEAT]      131072  -> 1212416  (4 packed entries/row)
// 1212416  ovf_desc int  [D_FEAT]      32768   -> 1245184  ((start<<5)|extra)
// 1245184  ovf_ents int  [OVF_CAP]     65536   -> 1310720
// 1310720  ovf_base int  [1]           4

__global__ void k_zero(int* __restrict__ row_cnt, int* __restrict__ ovf_base) {
    int t = blockIdx.x * blockDim.x + threadIdx.x;
    if (t < D_FEAT) row_cnt[t] = 0;
    if (t == 0)     ovf_base[0] = 0;
}

// Full-BW streaming scan of P (128MB), binning nonzeros directly into row lists.
__global__ void k_scan(const f32x4* __restrict__ p4,
                       int* __restrict__ row_cnt, int2* __restrict__ row_ent) {
    const long total = (long)D_FEAT * D_IN / 4;
    for (long q = (long)blockIdx.x * blockDim.x + threadIdx.x; q < total;
         q += (long)gridDim.x * blockDim.x) {
        f32x4 v = __builtin_nontemporal_load(&p4[q]);
        long base = q * 4;
        float vals[4] = {v.x, v.y, v.z, v.w};
        #pragma unroll
        for (int c = 0; c < 4; ++c) {
            if (vals[c] != 0.0f) {
                long i = base + c;
                int f = (int)(i >> 12);          // / D_IN
                int d = (int)(i & (D_IN - 1));   // % D_IN
                int slot = atomicAdd(&row_cnt[f], 1);
                if (slot < CAP) row_ent[f * CAP + slot] = make_int2(d, __float_as_int(vals[c]));
            }
        }
    }
}

// Per row f: sort entries by d (distinct -> deterministic), pack first 4 into
// int4 (entry = d*4 | sign<<31; dummy = D_IN*4 -> zeroed pad word; bit30 of .w =
// overflow flag), extras -> atomically-allocated compact slab. Slab offsets vary
// run-to-run but per-row entry ORDER doesn't -> bitwise-deterministic output.
__global__ void k_sortpack(const int* __restrict__ row_cnt, int2* __restrict__ row_ent,
                           int4* __restrict__ ent4, int* __restrict__ ovf_desc,
                           int* __restrict__ ovf_ents, int* __restrict__ ovf_base) {
    int f = blockIdx.x * blockDim.x + threadIdx.x;
    if (f >= D_FEAT) return;
    int cnt = row_cnt[f];
    if (cnt > CAP) cnt = CAP;
    for (int a = 1; a < cnt; ++a) {
        int2 key = row_ent[f * CAP + a];
        int b = a - 1;
        while (b >= 0) {
            int2 cur = row_ent[f * CAP + b];
            if (cur.x <= key.x) break;
            row_ent[f * CAP + b + 1] = cur;
            --b;
        }
        row_ent[f * CAP + b + 1] = key;
    }
    int e[4];
    #pragma unroll
    for (int j = 0; j < 4; ++j) {
        if (j < cnt) {
            int2 ev = row_ent[f * CAP + j];
            e[j] = (ev.x * 4) | (int)((unsigned)ev.y & 0x80000000u);
        } else {
            e[j] = D_IN * 4;   // dummy -> zeroed pad word
        }
    }
    int extra = (cnt > 4) ? (cnt - 4) : 0;
    int start = 0;
    if (extra) {
        start = atomicAdd(ovf_base, extra);
        if (start < 0) start = 0;
        if (start > OVF_CAP - CAP) start = OVF_CAP - CAP;   // capacity guard
        for (int j = 0; j < extra; ++j) {
            int2 ev = row_ent[f * CAP + 4 + j];
            ovf_ents[start + j] = (ev.x * 4) | (int)((unsigned)ev.y & 0x80000000u);
        }
        e[3] |= 0x40000000;
    }
    ovf_desc[f] = (start << 5) | extra;
    ent4[f] = make_int4(e[0], e[1], e[2], e[3]);
}

// Direct global->LDS 16B async copy (no VGPR round-trip). LDS dest is
// wave-uniform base + lane*16; global src is per-lane.
__device__ __forceinline__ void load_lds16(const float* g, float* l) {
    __builtin_amdgcn_global_load_lds(
        (const __attribute__((address_space(1))) void*)g,
        (__attribute__((address_space(3))) void*)l, 16, 0, 0);
}

// Main gather: one 4-row group per block, single barrier, 2 blocks/CU.
__global__ __launch_bounds__(1024, 8) void k_gather(const float* __restrict__ x,
                                                    const int4* __restrict__ ent4,
                                                    const int* __restrict__ ovf_desc,
                                                    const int* __restrict__ ovf_ents,
                                                    float* __restrict__ out) {
    __shared__ float xs[NR * ROWW];   // 65,664 B -> 2 blocks/CU
    const int n0 = blockIdx.x * NR;
    const int tid = threadIdx.x;
    const int wav = tid >> 6;

    // Prefetch first-half structure quads: they land under the staging loads.
    const int fb0 = tid * FPT;
    int4 e0 = ent4[fb0 + 0];
    int4 e1 = ent4[fb0 + 1];
    int4 e2 = ent4[fb0 + 2];
    int4 e3 = ent4[fb0 + 3];

    // Stage rows n0..n0+3 row-major via global_load_lds(16B): per wave the LDS
    // dest is uniform base + lane*16 = 256 consecutive words -> linear; rows at
    // r*ROWW. Global src per-lane, fully coalesced (1KB/wave/instr).
    {
        const float* gb = x + (size_t)n0 * D_IN + tid * 4;
        float* lb = xs + wav * 256;
        load_lds16(gb,             lb);
        load_lds16(gb + D_IN,      lb + ROWW);
        load_lds16(gb + 2 * D_IN,  lb + 2 * ROWW);
        load_lds16(gb + 3 * D_IN,  lb + 3 * ROWW);
    }
    // zero the pad words (dummy entries read word D_IN of each row)
    if (tid < NR * PADW) xs[(tid >> 3) * ROWW + D_IN + (tid & 7)] = 0.f;
    __syncthreads();   // implicit vmcnt(0): staging + prefetched quads landed

    const char* xsb  = (const char*)xs;                 // rows 0,1
    const char* xsb2 = (const char*)(xs + 2 * ROWW);    // rows 2,3 (imm range)
    float* o0 = out + (size_t)n0 * D_FEAT;
    float* o1 = o0 + D_FEAT;
    float* o2 = o1 + D_FEAT;
    float* o3 = o2 + D_FEAT;

    // ENT adds one packed entry (byte-off | sign<<31) to the 4 row-accumulators.
    #define ENT(EE, A0, A1, A2, A3) { \
        int off_ = (EE) & 0x7FFC; \
        float v0_ = *(const float*)(xsb  + off_); \
        float v1_ = *(const float*)(xsb  + off_ + ROWW * 4); \
        float v2_ = *(const float*)(xsb2 + off_); \
        float v3_ = *(const float*)(xsb2 + off_ + ROWW * 4); \
        unsigned sg_ = (unsigned)(EE) & 0x80000000u; \
        A0 += __uint_as_float(__float_as_uint(v0_) ^ sg_); \
        A1 += __uint_as_float(__float_as_uint(v1_) ^ sg_); \
        A2 += __uint_as_float(__float_as_uint(v2_) ^ sg_); \
        A3 += __uint_as_float(__float_as_uint(v3_) ^ sg_); }

    #define HALF(E0, E1, E2, E3, FB) { \
        float a00=0,a01=0,a02=0,a03=0, a10=0,a11=0,a12=0,a13=0; \
        float a20=0,a21=0,a22=0,a23=0, a30=0,a31=0,a32=0,a33=0; \
        ENT(E0.x,a00,a01,a02,a03) ENT(E0.y,a00,a01,a02,a03) \
        ENT(E0.z,a00,a01,a02,a03) ENT(E0.w,a00,a01,a02,a03) \
        ENT(E1.x,a10,a11,a12,a13) ENT(E1.y,a10,a11,a12,a13) \
        ENT(E1.z,a10,a11,a12,a13) ENT(E1.w,a10,a11,a12,a13) \
        ENT(E2.x,a20,a21,a22,a23) ENT(E2.y,a20,a21,a22,a23) \
        ENT(E2.z,a20,a21,a22,a23) ENT(E2.w,a20,a21,a22,a23) \
        ENT(E3.x,a30,a31,a32,a33) ENT(E3.y,a30,a31,a32,a33) \
        ENT(E3.z,a30,a31,a32,a33) ENT(E3.w,a30,a31,a32,a33) \
        if ((E0.w | E1.w | E2.w | E3.w) & 0x40000000) {   /* rare tails */ \
            if (E0.w & 0x40000000) { int od = ovf_desc[(FB)+0]; int ex = od & 31; \
                const int* oe = ovf_ents + (od >> 5); \
                for (int j = 0; j < ex; ++j) { int ee = oe[j]; ENT(ee,a00,a01,a02,a03) } } \
            if (E1.w & 0x40000000) { int od = ovf_desc[(FB)+1]; int ex = od & 31; \
                const int* oe = ovf_ents + (od >> 5); \
                for (int j = 0; j < ex; ++j) { int ee = oe[j]; ENT(ee,a10,a11,a12,a13) } } \
            if (E2.w & 0x40000000) { int od = ovf_desc[(FB)+2]; int ex = od & 31; \
                const int* oe = ovf_ents + (od >> 5); \
                for (int j = 0; j < ex; ++j) { int ee = oe[j]; ENT(ee,a20,a21,a22,a23) } } \
            if (E3.w & 0x40000000) { int od = ovf_desc[(FB)+3]; int ex = od & 31; \
                const int* oe = ovf_ents + (od >> 5); \
                for (int j = 0; j < ex; ++j) { int ee = oe[j]; ENT(ee,a30,a31,a32,a33) } } \
        } \
        f32x4 r0 = {a00*0.5f, a10*0.5f, a20*0.5f, a30*0.5f}; \
        f32x4 r1 = {a01*0.5f, a11*0.5f, a21*0.5f, a31*0.5f}; \
        f32x4 r2 = {a02*0.5f, a12*0.5f, a22*0.5f, a32*0.5f}; \
        f32x4 r3 = {a03*0.5f, a13*0.5f, a23*0.5f, a33*0.5f}; \
        __builtin_nontemporal_store(r0, (f32x4*)((o0) + (FB))); \
        __builtin_nontemporal_store(r1, (f32x4*)((o1) + (FB))); \
        __builtin_nontemporal_store(r2, (f32x4*)((o2) + (FB))); \
        __builtin_nontemporal_store(r3, (f32x4*)((o3) + (FB))); }

    // Half A: features [0, 4096), quads prefetched in prologue.
    HALF(e0, e1, e2, e3, fb0)

    // Half B: features [4096, 8192); loads hidden by inter-wave TLP.
    const int fb1 = fb0 + D_FEAT / 2;
    int4 g0 = ent4[fb1 + 0];
    int4 g1 = ent4[fb1 + 1];
    int4 g2 = ent4[fb1 + 2];
    int4 g3 = ent4[fb1 + 3];
    HALF(g0, g1, g2, g3, fb1)

    #undef HALF
    #undef ENT
}

extern "C" void kernel_launch(void* const* d_in, const int* in_sizes, int n_in,
                              void* d_out, int out_size, void* d_ws, size_t ws_size,
                              hipStream_t stream) {
    const float* x = (const float*)d_in[0];
    const float* P = (const float*)d_in[1];
    float* out = (float*)d_out;

    char* ws = (char*)d_ws;
    int*   row_cnt  = (int*)  (ws + 0);
    int2*  row_ent  = (int2*) (ws + 32768);
    int4*  ent4     = (int4*) (ws + 1081344);
    int*   ovf_desc = (int*)  (ws + 1212416);
    int*   ovf_ents = (int*)  (ws + 1245184);
    int*   ovf_base = (int*)  (ws + 1310720);

    k_zero    <<<(D_FEAT + 255) / 256, 256, 0, stream>>>(row_cnt, ovf_base);
    k_scan    <<<2048, 256, 0, stream>>>((const f32x4*)P, row_cnt, row_ent);
    k_sortpack<<<(D_FEAT + 255) / 256, 256, 0, stream>>>(row_cnt, row_ent, ent4,
                                                         ovf_desc, ovf_ents, ovf_base);
    k_gather  <<<N_TOT / NR, 1024, 0, stream>>>(x, ent4, ovf_desc, ovf_ents, out);
}